// Round 4
// baseline (421.038 us; speedup 1.0000x reference)
//
#include <hip/hip_runtime.h>

#define BLOCK 256
#define C_DIM 10000
#define C4 (C_DIM / 4)
#define NIT ((C4 + BLOCK - 1) / BLOCK)   // 10
#define TAU 1.0f
#define PIV 2.0f
#define SEG 4
#define SEGLEN (C_DIM / SEG)             // 2500
#define SEGLEN4 (SEGLEN / 4)             // 625
#define MAXCAP 2048

// Monotone bijection float -> uint32 (larger float => larger key)
__device__ __forceinline__ unsigned flip_key(float f) {
    unsigned u = __float_as_uint(f);
    return (u & 0x80000000u) ? ~u : (u | 0x80000000u);
}
__device__ __forceinline__ float unflip_key(unsigned k) {
    unsigned u = (k & 0x80000000u) ? (k & 0x7fffffffu) : ~k;
    return __uint_as_float(u);
}

__global__ void init_kernel(float* out, int out_n, float* z, unsigned* madj,
                            unsigned* cnt, int B) {
    int i = blockIdx.x * blockDim.x + threadIdx.x;
    if (i < out_n) out[i] = 0.f;
    if (i < B) { z[i] = 0.f; madj[i] = 0u; cnt[i] = 0u; }
}

// Wave-aggregated candidate append: one row-counter atomic per wave per call.
__device__ __forceinline__ void append_cand(bool m, float v, int idx, int lane,
                                            unsigned* g_cnt_row,
                                            float* __restrict__ cv,
                                            unsigned short* __restrict__ ci, int cap) {
    unsigned long long mk = __ballot(m);
    if (mk == 0ull) return;                       // wave-uniform
    int leader = (int)(__ffsll((unsigned long long)mk) - 1);
    unsigned n = (unsigned)__popcll(mk);
    unsigned base = 0u;
    if (lane == leader) base = atomicAdd(g_cnt_row, n);
    base = (unsigned)__shfl((int)base, leader);
    if (m) {
        unsigned pos = base + (unsigned)__popcll(mk & ((1ull << lane) - 1ull));
        if (pos < (unsigned)cap) { cv[pos] = v; ci[pos] = (unsigned short)idx; }
    }
}

// ---- K1: pure streaming. 4 segment-blocks per row.
__global__ __launch_bounds__(BLOCK) void stream_kernel(
    const float* __restrict__ logit, const float* __restrict__ lcn,
    float* __restrict__ g_z, unsigned* __restrict__ g_madj,
    unsigned* __restrict__ g_cnt, float* __restrict__ candval,
    unsigned short* __restrict__ candidx, int cap) {
    __shared__ float red_z[4], red_m[4];
    const int row = blockIdx.x / SEG;
    const int seg = blockIdx.x % SEG;
    const int tid = threadIdx.x;
    const int lane = tid & 63;
    const int wid = tid >> 6;

    const float* lr = logit + (size_t)row * C_DIM + seg * SEGLEN;
    const float* lc = lcn + seg * SEGLEN;
    float* cv = candval + (size_t)row * cap;
    unsigned short* ci = candidx + (size_t)row * cap;

    float z = 0.f, madj = -INFINITY;
    for (int j4 = tid; j4 < SEGLEN4; j4 += BLOCK) {
        float4 f = ((const float4*)lr)[j4];
        float4 l = ((const float4*)lc)[j4];
        float a0 = f.x + TAU * l.x, a1 = f.y + TAU * l.y;
        float a2 = f.z + TAU * l.z, a3 = f.w + TAU * l.w;
        z += __expf(a0) + __expf(a1) + __expf(a2) + __expf(a3);
        madj = fmaxf(madj, fmaxf(fmaxf(a0, a1), fmaxf(a2, a3)));
        int j = seg * SEGLEN + 4 * j4;
        append_cand(f.x >= PIV, f.x, j + 0, lane, &g_cnt[row], cv, ci, cap);
        append_cand(f.y >= PIV, f.y, j + 1, lane, &g_cnt[row], cv, ci, cap);
        append_cand(f.z >= PIV, f.z, j + 2, lane, &g_cnt[row], cv, ci, cap);
        append_cand(f.w >= PIV, f.w, j + 3, lane, &g_cnt[row], cv, ci, cap);
    }
    for (int off = 32; off; off >>= 1) {
        z += __shfl_down(z, off);
        madj = fmaxf(madj, __shfl_down(madj, off));
    }
    if (lane == 0) { red_z[wid] = z; red_m[wid] = madj; }
    __syncthreads();
    if (tid == 0) {
        float zb = red_z[0] + red_z[1] + red_z[2] + red_z[3];
        float mb = fmaxf(fmaxf(red_m[0], red_m[1]), fmaxf(red_m[2], red_m[3]));
        atomicAdd(&g_z[row], zb);
        atomicMax(&g_madj[row], flip_key(mb));
    }
}

// Wave 0 (tid<64): suffix-scan 256 bins (4/lane), pick the bin containing the
// kr-th largest; update prefix / kr / selected-bin count. Exactly one lane writes.
__device__ __forceinline__ void scan_pick(unsigned* hist, int shift, int tid,
                                          unsigned* shp, unsigned* shkr, unsigned* shcnt) {
    unsigned h0 = hist[4 * tid + 0], h1 = hist[4 * tid + 1];
    unsigned h2 = hist[4 * tid + 2], h3 = hist[4 * tid + 3];
    unsigned loc = h0 + h1 + h2 + h3;
    unsigned suf = loc;
    for (int off = 1; off < 64; off <<= 1) {
        unsigned o = __shfl_down(suf, off);
        if (tid + off < 64) suf += o;
    }
    unsigned sufex = suf - loc;
    unsigned kr = *shkr;
    unsigned s3 = sufex + h3;
    unsigned s2 = s3 + h2;
    unsigned s1 = s2 + h1;
    unsigned s0 = s1 + h0;
    int bsel = -1; unsigned newkr = 0, newcnt = 0;
    if      (s3 >= kr && s3 - h3 < kr) { bsel = 4 * tid + 3; newkr = kr - (s3 - h3); newcnt = h3; }
    else if (s2 >= kr && s2 - h2 < kr) { bsel = 4 * tid + 2; newkr = kr - (s2 - h2); newcnt = h2; }
    else if (s1 >= kr && s1 - h1 < kr) { bsel = 4 * tid + 1; newkr = kr - (s1 - h1); newcnt = h1; }
    else if (s0 >= kr && s0 - h0 < kr) { bsel = 4 * tid + 0; newkr = kr - (s0 - h0); newcnt = h0; }
    if (bsel >= 0) {
        *shp |= ((unsigned)bsel << shift);
        *shkr = newkr;
        *shcnt = newcnt;
    }
}

// ---- K2: per-row select + masked sum + epilogue. One block per row.
__global__ __launch_bounds__(BLOCK) void select_kernel(
    const float* __restrict__ logit, const int* __restrict__ target,
    const float* __restrict__ lcn, const int* __restrict__ kpc,
    const float* __restrict__ g_z, const unsigned* __restrict__ g_madj,
    const unsigned* __restrict__ g_cnt, const float* __restrict__ candval,
    const unsigned short* __restrict__ candidx, int cap,
    float* __restrict__ out, int B) {
    __shared__ unsigned candk[MAXCAP];
    __shared__ unsigned hist[256];
    __shared__ float red_a[4], red_b[4];
    __shared__ unsigned sh_prefix, sh_kr, sh_cnt;
    __shared__ float sh_thresh;

    const int row = blockIdx.x;
    const int tid = threadIdx.x;
    const int lane = tid & 63;
    const int wid = tid >> 6;
    const float* lrow = logit + (size_t)row * C_DIM;

    const int t = target[row];
    int k = kpc[t]; if (k > C_DIM) k = C_DIM;
    const unsigned nc = g_cnt[row];
    const float madj = unflip_key(g_madj[row]);
    const float Zws = g_z[row];
    const bool rare = fabsf(madj) > 80.f;
    const bool normal = (!rare) && (cap > 0) && (nc >= (unsigned)k) && (nc <= (unsigned)cap);

    float sm = 0.f, zloc = 0.f;

    if (normal) {
        const float* cv = candval + (size_t)row * cap;
        const unsigned short* ci = candidx + (size_t)row * cap;
        for (int i = tid; i < (int)nc; i += BLOCK) candk[i] = __float_as_uint(cv[i]);
        if (tid == 0) { sh_prefix = 0u; sh_kr = (unsigned)k; sh_cnt = nc; }
        __syncthreads();

        unsigned kmask = 0u;
        for (int q = 0; q < 4; ++q) {
            if (sh_cnt == 1u) break;               // block-uniform
            const int shift = 24 - 8 * q;
            hist[tid] = 0u;
            __syncthreads();
            const unsigned pref = sh_prefix;
            for (int i = tid; i < (int)nc; i += BLOCK) {
                unsigned kk = candk[i];
                if ((kk & kmask) == pref) atomicAdd(&hist[(kk >> shift) & 0xFFu], 1u);
            }
            __syncthreads();
            if (tid < 64) scan_pick(hist, shift, tid, &sh_prefix, &sh_kr, &sh_cnt);
            kmask |= (0xFFu << shift);
            __syncthreads();
        }
        if (sh_cnt == 1u && kmask != 0xFFFFFFFFu) {
            const unsigned pref = sh_prefix;
            __syncthreads();
            for (int i = tid; i < (int)nc; i += BLOCK) {
                unsigned kk = candk[i];
                if ((kk & kmask) == pref) sh_prefix = kk;   // unique (or dup value)
            }
            __syncthreads();
        }
        if (tid == 0) sh_thresh = __uint_as_float(sh_prefix);
        __syncthreads();

        const float thresh = sh_thresh;
        for (int i = tid; i < (int)nc; i += BLOCK) {
            float v = __uint_as_float(candk[i]);
            if (v >= thresh) sm += __expf(v + TAU * lcn[ci[i]]);
        }
    } else {
        // ---- Cold fallback: full-row radix on flipped keys + full sweep
        if (tid == 0) { sh_prefix = 0u; sh_kr = (unsigned)k; sh_cnt = (unsigned)C_DIM; }
        for (int p = 0; p < 4; ++p) {
            const int shift = 24 - 8 * p;
            const unsigned pmask = p ? (0xFFFFFFFFu << (shift + 8)) : 0u;
            hist[tid] = 0u;
            __syncthreads();
            const unsigned pref = sh_prefix;
            for (int it = 0; it < NIT; ++it) {
                int j4 = it * BLOCK + tid;
                if (j4 < C4) {
                    float4 f = ((const float4*)lrow)[j4];
                    unsigned kk;
                    kk = flip_key(f.x); if ((kk & pmask) == pref) atomicAdd(&hist[(kk >> shift) & 0xFFu], 1u);
                    kk = flip_key(f.y); if ((kk & pmask) == pref) atomicAdd(&hist[(kk >> shift) & 0xFFu], 1u);
                    kk = flip_key(f.z); if ((kk & pmask) == pref) atomicAdd(&hist[(kk >> shift) & 0xFFu], 1u);
                    kk = flip_key(f.w); if ((kk & pmask) == pref) atomicAdd(&hist[(kk >> shift) & 0xFFu], 1u);
                }
            }
            __syncthreads();
            if (tid < 64) scan_pick(hist, shift, tid, &sh_prefix, &sh_kr, &sh_cnt);
            __syncthreads();
        }
        if (tid == 0) sh_thresh = unflip_key(sh_prefix);
        __syncthreads();

        const float thresh = sh_thresh;
        const float sub = rare ? madj : 0.f;
        for (int it = 0; it < NIT; ++it) {
            int j4 = it * BLOCK + tid;
            if (j4 < C4) {
                float4 f = ((const float4*)lrow)[j4];
                float4 l = ((const float4*)lcn)[j4];
                float e;
                e = __expf(f.x + TAU * l.x - sub); zloc += e; if (f.x >= thresh) sm += e;
                e = __expf(f.y + TAU * l.y - sub); zloc += e; if (f.y >= thresh) sm += e;
                e = __expf(f.z + TAU * l.z - sub); zloc += e; if (f.z >= thresh) sm += e;
                e = __expf(f.w + TAU * l.w - sub); zloc += e; if (f.w >= thresh) sm += e;
            }
        }
    }

    for (int off = 32; off; off >>= 1) {
        sm   += __shfl_down(sm, off);
        zloc += __shfl_down(zloc, off);
    }
    if (lane == 0) { red_a[wid] = zloc; red_b[wid] = sm; }
    __syncthreads();

    if (tid == 0) {
        float S  = red_b[0] + red_b[1] + red_b[2] + red_b[3];
        float Zu = normal ? Zws : (red_a[0] + red_a[1] + red_a[2] + red_a[3]);
        float thresh = sh_thresh;
        float logit_t = lrow[t];
        float adj_t = logit_t + TAU * lcn[t];
        float sub = rare ? madj : 0.f;
        float lpt = adj_t - sub - __logf(Zu);            // log_p_adj[target]
        float p_num = ((logit_t >= thresh) ? __expf(lpt) : 0.f) + 1e-6f;
        float Smask = S / Zu + (float)C_DIM * 1e-6f;
        float loss = 0.5f * (-lpt + __logf(Smask) - __logf(p_num));
        atomicAdd(out, loss / (float)B);
    }
}

extern "C" void kernel_launch(void* const* d_in, const int* in_sizes, int n_in,
                              void* d_out, int out_size, void* d_ws, size_t ws_size,
                              hipStream_t stream) {
    const float* logit  = (const float*)d_in[0];
    const int*   target = (const int*)d_in[1];
    const float* lcn    = (const float*)d_in[2];
    const int*   kpc    = (const int*)d_in[3];
    float* out = (float*)d_out;
    const int B = in_sizes[1];   // target is [B]

    char* ws = (char*)d_ws;
    float*    g_z    = (float*)ws;
    unsigned* g_madj = (unsigned*)(ws + (size_t)B * 4);
    unsigned* g_cnt  = (unsigned*)(ws + (size_t)B * 8);
    size_t fixed = (size_t)B * 12;
    int cap = 0;
    if (ws_size > fixed) {
        size_t c = (ws_size - fixed) / ((size_t)B * 6);
        cap = (c > (size_t)MAXCAP) ? MAXCAP : (int)c;
        if (cap < 4) cap = 0;   // too small to be useful -> always fallback
    }
    float* candval = (float*)(ws + fixed);
    unsigned short* candidx = (unsigned short*)(ws + fixed + (size_t)B * (size_t)cap * 4);

    int initn = (out_size > B) ? out_size : B;
    init_kernel<<<(initn + 255) / 256, 256, 0, stream>>>(out, out_size, g_z, g_madj, g_cnt, B);
    stream_kernel<<<B * SEG, BLOCK, 0, stream>>>(logit, lcn, g_z, g_madj, g_cnt,
                                                 candval, candidx, cap);
    select_kernel<<<B, BLOCK, 0, stream>>>(logit, target, lcn, kpc, g_z, g_madj, g_cnt,
                                           candval, candidx, cap, out, B);
}

// Round 6
// 278.495 us; speedup vs baseline: 1.5118x; 1.5118x over previous
//
#include <hip/hip_runtime.h>

#define BLOCK 256
#define C_DIM 10000
#define C4 (C_DIM / 4)            // 2500 float4 per row
#define NIT ((C4 + BLOCK - 1) / BLOCK)   // 10 (fallback path only)
#define TAU 1.0f
#define PIV 2.0f
#define CAP 1024

// Monotone bijection float -> uint32 (larger float => larger key)
__device__ __forceinline__ unsigned flip_key(float f) {
    unsigned u = __float_as_uint(f);
    return (u & 0x80000000u) ? ~u : (u | 0x80000000u);
}
__device__ __forceinline__ float unflip_key(unsigned k) {
    unsigned u = (k & 0x80000000u) ? (k & 0x7fffffffu) : ~k;
    return __uint_as_float(u);
}

__global__ void zero_out_kernel(float* out, int n) {
    int i = blockIdx.x * blockDim.x + threadIdx.x;
    if (i < n) out[i] = 0.f;
}

// Wave 0 (tid<64): suffix-scan 256 bins (4/lane), pick the bin containing the
// kr-th largest; update prefix / kr / selected-bin count. Exactly one lane writes.
__device__ __forceinline__ void scan_pick(unsigned* hist, int shift, int tid,
                                          unsigned* shp, unsigned* shkr, unsigned* shcnt) {
    unsigned h0 = hist[4 * tid + 0], h1 = hist[4 * tid + 1];
    unsigned h2 = hist[4 * tid + 2], h3 = hist[4 * tid + 3];
    unsigned loc = h0 + h1 + h2 + h3;
    unsigned suf = loc;
    for (int off = 1; off < 64; off <<= 1) {
        unsigned o = __shfl_down(suf, off);
        if (tid + off < 64) suf += o;
    }
    unsigned sufex = suf - loc;            // sum over bins strictly above my 4
    unsigned kr = *shkr;
    unsigned s3 = sufex + h3;
    unsigned s2 = s3 + h2;
    unsigned s1 = s2 + h1;
    unsigned s0 = s1 + h0;
    int bsel = -1; unsigned newkr = 0, newcnt = 0;
    if      (s3 >= kr && s3 - h3 < kr) { bsel = 4 * tid + 3; newkr = kr - (s3 - h3); newcnt = h3; }
    else if (s2 >= kr && s2 - h2 < kr) { bsel = 4 * tid + 2; newkr = kr - (s2 - h2); newcnt = h2; }
    else if (s1 >= kr && s1 - h1 < kr) { bsel = 4 * tid + 1; newkr = kr - (s1 - h1); newcnt = h1; }
    else if (s0 >= kr && s0 - h0 < kr) { bsel = 4 * tid + 0; newkr = kr - (s0 - h0); newcnt = h0; }
    if (bsel >= 0) {
        *shp |= ((unsigned)bsel << shift);
        *shkr = newkr;
        *shcnt = newcnt;
    }
}

// Streaming-pass element processing: exp-accumulate, track max, compact >= PIV
// via per-lane LDS atomic append. NOTE: internal index var is _pj to avoid
// shadowing any call-site identifier (R5's bug: `int jb = 4*(jb)` self-init UB).
#define PROC4(f, l, j4)                                                              \
    {                                                                                \
        float a0 = (f).x + TAU * (l).x, a1 = (f).y + TAU * (l).y;                    \
        float a2 = (f).z + TAU * (l).z, a3 = (f).w + TAU * (l).w;                    \
        z0 += __expf(a0); z1 += __expf(a1); z2 += __expf(a2); z3 += __expf(a3);      \
        madj = fmaxf(madj, fmaxf(fmaxf(a0, a1), fmaxf(a2, a3)));                     \
        const int _pj = 4 * (j4);                                                    \
        if ((f).x >= PIV) { unsigned i = atomicAdd(&sh_nc, 1u); if (i < CAP) { candk[i] = __float_as_uint((f).x); candi[i] = (unsigned short)(_pj + 0); } } \
        if ((f).y >= PIV) { unsigned i = atomicAdd(&sh_nc, 1u); if (i < CAP) { candk[i] = __float_as_uint((f).y); candi[i] = (unsigned short)(_pj + 1); } } \
        if ((f).z >= PIV) { unsigned i = atomicAdd(&sh_nc, 1u); if (i < CAP) { candk[i] = __float_as_uint((f).z); candi[i] = (unsigned short)(_pj + 2); } } \
        if ((f).w >= PIV) { unsigned i = atomicAdd(&sh_nc, 1u); if (i < CAP) { candk[i] = __float_as_uint((f).w); candi[i] = (unsigned short)(_pj + 3); } } \
    }

__global__ __launch_bounds__(BLOCK, 8) void topk_la_loss_kernel(
    const float* __restrict__ logit, const int* __restrict__ target,
    const float* __restrict__ lcn, const int* __restrict__ kpc,
    float* __restrict__ out, int B) {
    __shared__ unsigned candk[CAP];          // raw float bits (all >= 2.0 -> positive)
    __shared__ unsigned short candi[CAP];    // element index (for lcn gather)
    __shared__ unsigned hist[256];
    __shared__ float red_a[4], red_b[4];
    __shared__ unsigned sh_nc, sh_prefix, sh_kr, sh_cnt;
    __shared__ float sh_thresh, sh_Z, sh_madj;

    const int row = blockIdx.x;
    const int tid = threadIdx.x;
    const int lane = tid & 63;
    const int wid = tid >> 6;
    const float* lrow = logit + (size_t)row * C_DIM;

    const int t = target[row];                 // uniform scalar loads
    int k = kpc[t]; if (k > C_DIM) k = C_DIM;

    if (tid == 0) sh_nc = 0u;
    __syncthreads();

    // ---- Streaming sweep: z = sum exp(adj) (no max-sub; |madj|>80 guard),
    //      max(adj), compact logit >= PIV into LDS. 2x unrolled, batched loads.
    float z0 = 0.f, z1 = 0.f, z2 = 0.f, z3 = 0.f, madj = -INFINITY;
    const float4* lr4 = (const float4*)lrow;
    const float4* lc4 = (const float4*)lcn;
    for (int it = 0; it < 4; ++it) {
        int ja = it * (2 * BLOCK) + tid;       // 0..2047
        int jb = ja + BLOCK;
        float4 fa = lr4[ja];
        float4 fb = lr4[jb];
        float4 la = lc4[ja];
        float4 lb = lc4[jb];
        PROC4(fa, la, ja);
        PROC4(fb, lb, jb);
    }
    {   // j4 = 2048..2303 (full width)
        int j = 2048 + tid;
        float4 f = lr4[j];
        float4 l = lc4[j];
        PROC4(f, l, j);
    }
    if (tid < C4 - 2304) {                     // j4 = 2304..2499 tail
        int j = 2304 + tid;
        float4 f = lr4[j];
        float4 l = lc4[j];
        PROC4(f, l, j);
    }

    float z = (z0 + z1) + (z2 + z3);
    for (int off = 32; off; off >>= 1) {
        z += __shfl_down(z, off);
        madj = fmaxf(madj, __shfl_down(madj, off));
    }
    if (lane == 0) { red_a[wid] = z; red_b[wid] = madj; }
    __syncthreads();

    if (tid == 0) {
        sh_Z = red_a[0] + red_a[1] + red_a[2] + red_a[3];
        sh_madj = fmaxf(fmaxf(red_b[0], red_b[1]), fmaxf(red_b[2], red_b[3]));
        sh_prefix = 0u;
        sh_kr = (unsigned)k;
        sh_cnt = sh_nc;
    }
    __syncthreads();

    const unsigned nc = sh_nc;
    const float madjB = sh_madj;
    const bool rare = fabsf(madjB) > 80.f;
    const bool normal = (!rare) && (nc >= (unsigned)k) && (nc <= (unsigned)CAP);

    float sm = 0.f, zloc = 0.f;

    if (normal) {
        // ---- Exact byte-radix select over nc candidates in LDS
        unsigned kmask = 0u;
        for (int q = 0; q < 4; ++q) {
            if (sh_cnt == 1u) break;           // block-uniform
            const int shift = 24 - 8 * q;
            hist[tid] = 0u;
            __syncthreads();
            const unsigned pref = sh_prefix;
            for (int i = tid; i < (int)nc; i += BLOCK) {
                unsigned kk = candk[i];
                if ((kk & kmask) == pref) atomicAdd(&hist[(kk >> shift) & 0xFFu], 1u);
            }
            __syncthreads();
            if (tid < 64) scan_pick(hist, shift, tid, &sh_prefix, &sh_kr, &sh_cnt);
            kmask |= (0xFFu << shift);
            __syncthreads();
        }
        if (sh_cnt == 1u && kmask != 0xFFFFFFFFu) {
            const unsigned pref = sh_prefix;   // read before the single write
            __syncthreads();
            for (int i = tid; i < (int)nc; i += BLOCK) {
                unsigned kk = candk[i];
                if ((kk & kmask) == pref) sh_prefix = kk;   // unique value (dups benign)
            }
            __syncthreads();
        }
        if (tid == 0) sh_thresh = __uint_as_float(sh_prefix);
        __syncthreads();

        // ---- Masked numerator sum: subset of candidates, lcn gather L2-hot
        const float thresh = sh_thresh;
        for (int i = tid; i < (int)nc; i += BLOCK) {
            float v = __uint_as_float(candk[i]);
            if (v >= thresh) sm += __expf(v + TAU * lcn[candi[i]]);
        }
    } else {
        // ---- Cold fallback: full-row radix on flipped keys + full re-sweep
        for (int p = 0; p < 4; ++p) {
            const int shift = 24 - 8 * p;
            const unsigned pmask = p ? (0xFFFFFFFFu << (shift + 8)) : 0u;
            hist[tid] = 0u;
            __syncthreads();
            const unsigned pref = sh_prefix;
            for (int it = 0; it < NIT; ++it) {
                int j4 = it * BLOCK + tid;
                if (j4 < C4) {
                    float4 f = lr4[j4];
                    unsigned kk;
                    kk = flip_key(f.x); if ((kk & pmask) == pref) atomicAdd(&hist[(kk >> shift) & 0xFFu], 1u);
                    kk = flip_key(f.y); if ((kk & pmask) == pref) atomicAdd(&hist[(kk >> shift) & 0xFFu], 1u);
                    kk = flip_key(f.z); if ((kk & pmask) == pref) atomicAdd(&hist[(kk >> shift) & 0xFFu], 1u);
                    kk = flip_key(f.w); if ((kk & pmask) == pref) atomicAdd(&hist[(kk >> shift) & 0xFFu], 1u);
                }
            }
            __syncthreads();
            if (tid < 64) scan_pick(hist, shift, tid, &sh_prefix, &sh_kr, &sh_cnt);
            __syncthreads();
        }
        if (tid == 0) sh_thresh = unflip_key(sh_prefix);
        __syncthreads();

        const float thresh = sh_thresh;
        const float sub = rare ? madjB : 0.f;
        for (int it = 0; it < NIT; ++it) {
            int j4 = it * BLOCK + tid;
            if (j4 < C4) {
                float4 f = lr4[j4];
                float4 l = lc4[j4];
                float e;
                e = __expf(f.x + TAU * l.x - sub); zloc += e; if (f.x >= thresh) sm += e;
                e = __expf(f.y + TAU * l.y - sub); zloc += e; if (f.y >= thresh) sm += e;
                e = __expf(f.z + TAU * l.z - sub); zloc += e; if (f.z >= thresh) sm += e;
                e = __expf(f.w + TAU * l.w - sub); zloc += e; if (f.w >= thresh) sm += e;
            }
        }
    }

    // ---- Joint block reduction of sm (and zloc for fallback)
    for (int off = 32; off; off >>= 1) {
        sm   += __shfl_down(sm, off);
        zloc += __shfl_down(zloc, off);
    }
    if (lane == 0) { red_a[wid] = zloc; red_b[wid] = sm; }
    __syncthreads();

    if (tid == 0) {
        float S  = red_b[0] + red_b[1] + red_b[2] + red_b[3];
        float Zu = normal ? sh_Z : (red_a[0] + red_a[1] + red_a[2] + red_a[3]);
        float thresh = sh_thresh;
        float logit_t = lrow[t];
        float adj_t = logit_t + TAU * lcn[t];
        float sub = rare ? madjB : 0.f;
        float lpt = adj_t - sub - __logf(Zu);            // log_p_adj[target]
        float p_num = ((logit_t >= thresh) ? __expf(lpt) : 0.f) + 1e-6f;
        float Smask = S / Zu + (float)C_DIM * 1e-6f;
        float loss = 0.5f * (-lpt + __logf(Smask) - __logf(p_num));
        atomicAdd(out, loss / (float)B);
    }
}

extern "C" void kernel_launch(void* const* d_in, const int* in_sizes, int n_in,
                              void* d_out, int out_size, void* d_ws, size_t ws_size,
                              hipStream_t stream) {
    const float* logit  = (const float*)d_in[0];
    const int*   target = (const int*)d_in[1];
    const float* lcn    = (const float*)d_in[2];
    const int*   kpc    = (const int*)d_in[3];
    float* out = (float*)d_out;
    const int B = in_sizes[1];   // target is [B]

    zero_out_kernel<<<1, 64, 0, stream>>>(out, out_size);
    topk_la_loss_kernel<<<B, BLOCK, 0, stream>>>(logit, target, lcn, kpc, out, B);
}